// Round 1
// baseline (506.605 us; speedup 1.0000x reference)
//
#include <hip/hip_runtime.h>
#include <stdint.h>

#define BB 512
#define TT 1024
#define KK 48
#define PF 8

// mask may arrive as 1-byte bools (raw numpy) or as 4-byte words.
// mask[0][0..3] are guaranteed true (len >= T/2), so the first 32-bit word is
// 0x01010101 iff byte storage. (If stored as int32 or float32 the first word
// is 1 or 0x3f800000 — both handled by the word path's nonzero test.)
__device__ __forceinline__ int mask_at(const void* m, int idx, bool bytes) {
    return bytes ? (int)(((const uint8_t*)m)[idx] != 0)
                 : (int)(((const int*)m)[idx] != 0);
}

// ---------------- forward algorithm: one wave per batch row ----------------
__global__ __launch_bounds__(64) void crf_fwd(
    const float* __restrict__ em, const void* __restrict__ mask,
    const float* __restrict__ trans, const float* __restrict__ start,
    const float* __restrict__ endt, float* __restrict__ ws)
{
    const int b = blockIdx.x;
    const int lane = threadIdx.x;
    const bool active = lane < KK;
    const int j = active ? lane : KK - 1;   // clamp for safe loads

    __shared__ __align__(16) float p_lds[64];

    const bool mb = (*(const int*)mask) == 0x01010101;

    // sequence length = popcount of prefix mask
    int cnt = 0;
    for (int t = lane; t < TT; t += 64) cnt += mask_at(mask, b * TT + t, mb);
    #pragma unroll
    for (int off = 32; off >= 1; off >>= 1) cnt += __shfl_xor(cnt, off);
    const int len = cnt;

    // E[i][j] = exp(trans[i][j]) for this lane's column j — 48 VGPRs
    float etr[KK];
    #pragma unroll
    for (int i = 0; i < KK; ++i)
        etr[i] = active ? __expf(trans[i * KK + j]) : 0.0f;

    const float* emb = em + (size_t)b * TT * KK;

    // t = 0 init: p[j] = exp(score0[j] - score0[0]), c = score0[0]
    float s0 = start[j] + emb[j];
    float c = __shfl(s0, 0);
    float pcur = active ? __expf(s0 - c) : 0.0f;
    p_lds[lane] = pcur;
    __syncthreads();

    // emission prefetch pipeline (depth PF) to keep HBM latency off the chain
    float pipe[PF];
    #pragma unroll
    for (int d = 0; d < PF; ++d) {
        int tt = 1 + d; tt = tt < TT ? tt : TT - 1;
        pipe[d] = emb[tt * KK + j];
    }

    int t = 1;
    while (t < len) {
        float cur[PF];
        #pragma unroll
        for (int d = 0; d < PF; ++d) cur[d] = pipe[d];
        #pragma unroll
        for (int d = 0; d < PF; ++d) {
            int tt = t + PF + d; tt = tt < TT ? tt : TT - 1;
            pipe[d] = emb[tt * KK + j];
        }
        #pragma unroll
        for (int d = 0; d < PF; ++d) {
            if (t + d < len) {
                // q[j] = sum_i p[i] * exp(trans[i][j])  — pure FMA matvec
                float q0 = 0.f, q1 = 0.f, q2 = 0.f, q3 = 0.f;
                #pragma unroll
                for (int i = 0; i < KK; i += 4) {
                    float4 pv = *(const float4*)&p_lds[i];  // broadcast read
                    q0 = fmaf(pv.x, etr[i],     q0);
                    q1 = fmaf(pv.y, etr[i + 1], q1);
                    q2 = fmaf(pv.z, etr[i + 2], q2);
                    q3 = fmaf(pv.w, etr[i + 3], q3);
                }
                float q  = (q0 + q1) + (q2 + q3);
                float pn = q * __expf(cur[d]);              // fold em_t in
                float r  = __shfl(pn, 0);                   // renormalizer
                c += __logf(r);                             // uniform on wave
                pcur = pn * __builtin_amdgcn_rcpf(r);
                __syncthreads();
                p_lds[lane] = pcur;
                __syncthreads();
            }
        }
        t += PF;
    }

    // log_z = c + log(sum_j p[j] * exp(end[j]))
    float v = active ? pcur * __expf(endt[j]) : 0.0f;
    #pragma unroll
    for (int off = 32; off >= 1; off >>= 1) v += __shfl_xor(v, off);
    if (lane == 0) ws[b] = c + __logf(v);
}

// ---------------- gold-path score: one 256-thread block per batch ----------
__global__ __launch_bounds__(256) void crf_seq(
    const float* __restrict__ em, const int* __restrict__ tags,
    const void* __restrict__ mask, const float* __restrict__ trans,
    const float* __restrict__ start, const float* __restrict__ endt,
    float* __restrict__ ws)
{
    const int b = blockIdx.x;
    const int tid = threadIdx.x;
    const bool mb = (*(const int*)mask) == 0x01010101;
    const float* emb = em + (size_t)b * TT * KK;
    const int* tgb = tags + b * TT;

    float s = 0.f;
    int cnt = 0;
    for (int t = tid; t < TT; t += 256) {
        int m = mask_at(mask, b * TT + t, mb);
        cnt += m;
        if (t > 0 && m) {
            int tp = tgb[t - 1], tc = tgb[t];
            s += trans[tp * KK + tc] + emb[t * KK + tc];
        }
    }
    __shared__ float sred[256];
    __shared__ int cred[256];
    sred[tid] = s; cred[tid] = cnt;
    __syncthreads();
    for (int off = 128; off > 0; off >>= 1) {
        if (tid < off) { sred[tid] += sred[tid + off]; cred[tid] += cred[tid + off]; }
        __syncthreads();
    }
    if (tid == 0) {
        int len = cred[0];
        int t0 = tgb[0];
        ws[BB + b] = sred[0] + start[t0] + emb[t0] + endt[tgb[len - 1]];
    }
}

// ---------------- final mean reduction ----------------
__global__ __launch_bounds__(256) void crf_final(const float* __restrict__ ws,
                                                 float* __restrict__ out)
{
    __shared__ float red[256];
    float s = 0.f;
    for (int b = threadIdx.x; b < BB; b += 256) s += ws[b] - ws[BB + b];
    red[threadIdx.x] = s;
    __syncthreads();
    for (int off = 128; off > 0; off >>= 1) {
        if (threadIdx.x < off) red[threadIdx.x] += red[threadIdx.x + off];
        __syncthreads();
    }
    if (threadIdx.x == 0) out[0] = red[0] / (float)BB;
}

extern "C" void kernel_launch(void* const* d_in, const int* in_sizes, int n_in,
                              void* d_out, int out_size, void* d_ws, size_t ws_size,
                              hipStream_t stream) {
    const float* em    = (const float*)d_in[0];
    const int*   tags  = (const int*)d_in[1];
    const void*  mask  = d_in[2];
    const float* trans = (const float*)d_in[3];
    const float* start = (const float*)d_in[4];
    const float* endt  = (const float*)d_in[5];
    float* ws  = (float*)d_ws;
    float* out = (float*)d_out;

    crf_fwd  <<<BB, 64,  0, stream>>>(em, mask, trans, start, endt, ws);
    crf_seq  <<<BB, 256, 0, stream>>>(em, tags, mask, trans, start, endt, ws);
    crf_final<<<1,  256, 0, stream>>>(ws, out);
}

// Round 2
// 391.097 us; speedup vs baseline: 1.2953x; 1.2953x over previous
//
#include <hip/hip_runtime.h>
#include <stdint.h>

#define BB 512
#define TT 1024
#define KK 48
#define PF 8

// mask may arrive as 1-byte bools (raw numpy) or as 4-byte words.
// mask[0][0..3] are guaranteed true (len >= T/2), so the first 32-bit word is
// 0x01010101 iff byte storage.
__device__ __forceinline__ int mask_at(const void* m, int idx, bool bytes) {
    return bytes ? (int)(((const uint8_t*)m)[idx] != 0)
                 : (int)(((const int*)m)[idx] != 0);
}

// wave-uniform broadcast from a fixed lane via v_readlane_b32 (SGPR result,
// no LDS pipe, no barrier)
__device__ __forceinline__ float bcast(float v, int lane) {
    return __int_as_float(__builtin_amdgcn_readlane(__float_as_int(v), lane));
}

// ------------- forward algorithm + fused gold-path score -------------------
// One wave per batch row. Lane j owns state j. The 48-wide all-to-all per
// step is done with v_readlane (VALU) instead of LDS round trips: the
// normalizer r = p[0] is the FIRST readlane result, so rcp/log overlap the
// remaining 47 readlane+FMA pairs. p is published unnormalized (q*exp(em))
// and divided by r on consumption — invariant: pcur = exp(S_t - c) exactly.
__global__ __launch_bounds__(64) void crf_fwd(
    const float* __restrict__ em, const int* __restrict__ tags,
    const void* __restrict__ mask, const float* __restrict__ trans,
    const float* __restrict__ start, const float* __restrict__ endt,
    float* __restrict__ ws)
{
    const int b = blockIdx.x;
    const int lane = threadIdx.x;
    const bool active = lane < KK;
    const int j = active ? lane : KK - 1;   // clamp for safe loads

    const bool mb = (*(const int*)mask) == 0x01010101;

    // sequence length = popcount of prefix mask
    int cnt = 0;
    for (int t = lane; t < TT; t += 64) cnt += mask_at(mask, b * TT + t, mb);
    #pragma unroll
    for (int off = 32; off >= 1; off >>= 1) cnt += __shfl_xor(cnt, off);
    const int len = cnt;

    // E[i][j] = exp(trans[i][j]) for this lane's column j — 48 VGPRs
    float etr[KK];
    #pragma unroll
    for (int i = 0; i < KK; ++i)
        etr[i] = active ? __expf(trans[i * KK + j]) : 0.0f;

    const float* emb = em + (size_t)b * TT * KK;

    // init: pcur = exp(S_0 - c), c = S_0[0]
    float s0 = start[j] + emb[j];
    float c = bcast(s0, 0);
    float pcur = active ? __expf(s0 - c) : 0.0f;

    // emission prefetch pipeline (depth PF) keeps HBM/L2 latency off the chain
    float pipe[PF];
    #pragma unroll
    for (int d = 0; d < PF; ++d) pipe[d] = emb[(1 + d) * KK + j];

    int t = 1;
    while (t < len) {
        float eexp[PF];
        #pragma unroll
        for (int d = 0; d < PF; ++d) eexp[d] = __expf(pipe[d]);   // off-chain
        #pragma unroll
        for (int d = 0; d < PF; ++d) {
            int tt = t + PF + d; tt = tt < TT ? tt : TT - 1;
            pipe[d] = emb[tt * KK + j];
        }
        #pragma unroll
        for (int d = 0; d < PF; ++d) {
            if (t + d < len) {
                float s00  = bcast(pcur, 0);                 // first readlane
                float rinv = __builtin_amdgcn_rcpf(s00);     // overlaps chain
                float scale = eexp[d] * rinv;                // overlaps chain
                float q[8];
                q[0] = s00 * etr[0];
                #pragma unroll
                for (int u = 1; u < 8; ++u) q[u] = 0.0f;
                #pragma unroll
                for (int k = 1; k < KK; ++k) {
                    float s = bcast(pcur, k);
                    q[k & 7] = fmaf(s, etr[k], q[k & 7]);
                }
                c += __logf(s00);                            // side chain
                float qs = ((q[0] + q[1]) + (q[2] + q[3]))
                         + ((q[4] + q[5]) + (q[6] + q[7]));
                pcur = qs * scale;
            }
        }
        t += PF;
    }

    // log_z = c + log(sum_j pcur_j * exp(end_j))
    float v = active ? pcur * __expf(endt[j]) : 0.0f;
    #pragma unroll
    for (int off = 32; off >= 1; off >>= 1) v += __shfl_xor(v, off);

    // ---- fused gold-path score (mask is prefix: m[t] == (t < len)) ----
    const int* tgb = tags + b * TT;
    float sq = 0.f;
    for (int tt2 = lane; tt2 < TT; tt2 += 64) {
        if (tt2 >= 1 && tt2 < len) {
            int tp = tgb[tt2 - 1], tc = tgb[tt2];
            sq += trans[tp * KK + tc] + emb[tt2 * KK + tc];
        }
    }
    #pragma unroll
    for (int off = 32; off >= 1; off >>= 1) sq += __shfl_xor(sq, off);

    if (lane == 0) {
        int t0 = tgb[0];
        ws[b]      = c + __logf(v);
        ws[BB + b] = sq + start[t0] + emb[t0] + endt[tgb[len - 1]];
    }
}

// ---------------- final mean reduction ----------------
__global__ __launch_bounds__(256) void crf_final(const float* __restrict__ ws,
                                                 float* __restrict__ out)
{
    __shared__ float red[256];
    float s = 0.f;
    for (int b = threadIdx.x; b < BB; b += 256) s += ws[b] - ws[BB + b];
    red[threadIdx.x] = s;
    __syncthreads();
    for (int off = 128; off > 0; off >>= 1) {
        if (threadIdx.x < off) red[threadIdx.x] += red[threadIdx.x + off];
        __syncthreads();
    }
    if (threadIdx.x == 0) out[0] = red[0] / (float)BB;
}

extern "C" void kernel_launch(void* const* d_in, const int* in_sizes, int n_in,
                              void* d_out, int out_size, void* d_ws, size_t ws_size,
                              hipStream_t stream) {
    const float* em    = (const float*)d_in[0];
    const int*   tags  = (const int*)d_in[1];
    const void*  mask  = d_in[2];
    const float* trans = (const float*)d_in[3];
    const float* start = (const float*)d_in[4];
    const float* endt  = (const float*)d_in[5];
    float* ws  = (float*)d_ws;
    float* out = (float*)d_out;

    crf_fwd  <<<BB, 64,  0, stream>>>(em, tags, mask, trans, start, endt, ws);
    crf_final<<<1,  256, 0, stream>>>(ws, out);
}

// Round 3
// 363.923 us; speedup vs baseline: 1.3921x; 1.0747x over previous
//
#include <hip/hip_runtime.h>
#include <stdint.h>

#define BB 512
#define TT 1024
#define KK 48
#define PF 8

// mask may arrive as 1-byte bools (raw numpy) or as 4-byte words.
// mask[0][0..3] are guaranteed true (len >= T/2), so the first 32-bit word is
// 0x01010101 iff byte storage.
__device__ __forceinline__ int mask_at(const void* m, int idx, bool bytes) {
    return bytes ? (int)(((const uint8_t*)m)[idx] != 0)
                 : (int)(((const int*)m)[idx] != 0);
}

// wave-uniform broadcast from a fixed lane via v_readlane_b32 (SGPR result,
// no LDS pipe, no barrier)
__device__ __forceinline__ float bcast(float v, int lane) {
    return __int_as_float(__builtin_amdgcn_readlane(__float_as_int(v), lane));
}

// ------------- forward algorithm + fused gold-path score -------------------
// One wave per batch row; lane j owns state j. Exp-domain recurrence
// p <- (E^T p) * exp(em_t) with E = exp(trans) resident in 48 VGPRs
// (__launch_bounds__(64,1) lifts the occupancy-driven VGPR cap so etr[] is
// NOT rematerialized per use — R2's 673 cyc/step pathology).
// Normalization deferred to every 4th step: growth/step <= 48*e^{0.1+em_max}
// ~= 2^15, so 4 steps <= 2^60 — safe in f32. rcp/log overlap the readlanes.
__global__ __launch_bounds__(64, 1) void crf_fwd(
    const float* __restrict__ em, const int* __restrict__ tags,
    const void* __restrict__ mask, const float* __restrict__ trans,
    const float* __restrict__ start, const float* __restrict__ endt,
    float* __restrict__ ws)
{
    const int b = blockIdx.x;
    const int lane = threadIdx.x;
    const bool active = lane < KK;
    const int j = active ? lane : KK - 1;   // clamp for safe loads

    const bool mb = (*(const int*)mask) == 0x01010101;

    // sequence length = popcount of prefix mask
    int cnt = 0;
    for (int t = lane; t < TT; t += 64) cnt += mask_at(mask, b * TT + t, mb);
    #pragma unroll
    for (int off = 32; off >= 1; off >>= 1) cnt += __shfl_xor(cnt, off);
    const int len = cnt;

    // E[i][j] = exp(trans[i][j]) for this lane's column j — 48 resident VGPRs
    float etr[KK];
    #pragma unroll
    for (int i = 0; i < KK; ++i)
        etr[i] = active ? __expf(trans[i * KK + j]) : 0.0f;

    const float* emb = em + (size_t)b * TT * KK;

    // init: pcur = exp(S_0 - c), c = S_0[0]
    float s0 = start[j] + emb[j];
    float c = bcast(s0, 0);
    float pcur = active ? __expf(s0 - c) : 0.0f;

    // emission prefetch pipeline (depth PF) keeps HBM/L2 latency off the chain
    float pipe[PF];
    #pragma unroll
    for (int d = 0; d < PF; ++d) pipe[d] = emb[(1 + d) * KK + j];

    int t = 1;
    while (t < len) {
        float eexp[PF];
        #pragma unroll
        for (int d = 0; d < PF; ++d) eexp[d] = __expf(pipe[d]);   // off-chain
        #pragma unroll
        for (int d = 0; d < PF; ++d) {
            int tt = t + PF + d; tt = tt < TT ? tt : TT - 1;
            pipe[d] = emb[tt * KK + j];
        }
        #pragma unroll
        for (int d = 0; d < PF; ++d) {
            if (t + d < len) {
                float scale = eexp[d];
                bool renorm = (d == 0) || (d == 4);
                float r = 0.0f;
                if (renorm) {
                    r = bcast(pcur, 0);                 // first readlane
                    scale *= __builtin_amdgcn_rcpf(r);  // overlaps RL sequence
                }
                float q0 = bcast(pcur, 0) * etr[0];
                float q1 = 0.f, q2 = 0.f, q3 = 0.f;
                #pragma unroll
                for (int k = 1; k < KK; k += 4) {
                    q1 = fmaf(bcast(pcur, k),     etr[k],     q1);
                    q2 = fmaf(bcast(pcur, k + 1), etr[k + 1], q2);
                    q3 = fmaf(bcast(pcur, k + 2), etr[k + 2], q3);
                    if (k + 3 < KK)
                        q0 = fmaf(bcast(pcur, k + 3), etr[k + 3], q0);
                }
                if (renorm) c += __logf(r);             // side chain
                float qs = (q0 + q1) + (q2 + q3);
                pcur = qs * scale;
            }
        }
        t += PF;
    }

    // final renorm + log_z = c + log(sum_j pcur_j * exp(end_j))
    float v = active ? pcur * __expf(endt[j]) : 0.0f;
    #pragma unroll
    for (int off = 32; off >= 1; off >>= 1) v += __shfl_xor(v, off);

    // ---- fused gold-path score (mask is prefix: m[t] == (t < len)) ----
    const int* tgb = tags + b * TT;
    float sq = 0.f;
    for (int tt2 = lane; tt2 < TT; tt2 += 64) {
        if (tt2 >= 1 && tt2 < len) {
            int tp = tgb[tt2 - 1], tc = tgb[tt2];
            sq += trans[tp * KK + tc] + emb[tt2 * KK + tc];
        }
    }
    #pragma unroll
    for (int off = 32; off >= 1; off >>= 1) sq += __shfl_xor(sq, off);

    if (lane == 0) {
        int t0 = tgb[0];
        ws[b]      = c + __logf(v);
        ws[BB + b] = sq + start[t0] + emb[t0] + endt[tgb[len - 1]];
    }
}

// ---------------- final mean reduction ----------------
__global__ __launch_bounds__(256) void crf_final(const float* __restrict__ ws,
                                                 float* __restrict__ out)
{
    __shared__ float red[256];
    float s = 0.f;
    for (int b = threadIdx.x; b < BB; b += 256) s += ws[b] - ws[BB + b];
    red[threadIdx.x] = s;
    __syncthreads();
    for (int off = 128; off > 0; off >>= 1) {
        if (threadIdx.x < off) red[threadIdx.x] += red[threadIdx.x + off];
        __syncthreads();
    }
    if (threadIdx.x == 0) out[0] = red[0] / (float)BB;
}

extern "C" void kernel_launch(void* const* d_in, const int* in_sizes, int n_in,
                              void* d_out, int out_size, void* d_ws, size_t ws_size,
                              hipStream_t stream) {
    const float* em    = (const float*)d_in[0];
    const int*   tags  = (const int*)d_in[1];
    const void*  mask  = d_in[2];
    const float* trans = (const float*)d_in[3];
    const float* start = (const float*)d_in[4];
    const float* endt  = (const float*)d_in[5];
    float* ws  = (float*)d_ws;
    float* out = (float*)d_out;

    crf_fwd  <<<BB, 64,  0, stream>>>(em, tags, mask, trans, start, endt, ws);
    crf_final<<<1,  256, 0, stream>>>(ws, out);
}

// Round 4
// 338.497 us; speedup vs baseline: 1.4966x; 1.0751x over previous
//
#include <hip/hip_runtime.h>
#include <stdint.h>

#define BB 512
#define TT 1024
#define KK 48
#define PF 8

// mask may arrive as 1-byte bools (raw numpy) or as 4-byte words.
// mask[0][0..3] are guaranteed true (len >= T/2), so the first 32-bit word is
// 0x01010101 iff byte storage.
__device__ __forceinline__ int mask_at(const void* m, int idx, bool bytes) {
    return bytes ? (int)(((const uint8_t*)m)[idx] != 0)
                 : (int)(((const int*)m)[idx] != 0);
}

// wave-uniform broadcast from a fixed lane via v_readlane_b32 (SGPR result,
// no LDS pipe, no barrier)
__device__ __forceinline__ float bcast(float v, int lane) {
    return __int_as_float(__builtin_amdgcn_readlane(__float_as_int(v), lane));
}

// ------------- forward algorithm + fused gold-path score -------------------
// One wave per batch row; lane j owns state j. Exp-domain recurrence
// p <- (E^T p) * exp(em_t), E = exp(trans) pinned in 48 VGPRs via opaque asm
// (R2/R3 showed VGPR_Count=52: LLVM was REMATERIALIZING etr from the
// invariant trans load at every FMA use site — reload+v_exp on the serial
// chain 48x/step). Renorm every 4th step; growth/step <= 48*e^{0.1+5.5}
// ~= 2^14, 4 steps ~= 2^56 — f32-safe both directions (measured absmax 0).
__global__ __launch_bounds__(64, 1) void crf_fwd(
    const float* __restrict__ em, const int* __restrict__ tags,
    const void* __restrict__ mask, const float* __restrict__ trans,
    const float* __restrict__ start, const float* __restrict__ endt,
    float* __restrict__ ws)
{
    const int b = blockIdx.x;
    const int lane = threadIdx.x;
    const bool active = lane < KK;
    const int j = active ? lane : KK - 1;   // clamp for safe loads

    const bool mb = (*(const int*)mask) == 0x01010101;

    // sequence length = popcount of prefix mask
    int cnt = 0;
    for (int t = lane; t < TT; t += 64) cnt += mask_at(mask, b * TT + t, mb);
    #pragma unroll
    for (int off = 32; off >= 1; off >>= 1) cnt += __shfl_xor(cnt, off);
    const int len = cnt;

    // E[i][j] = exp(trans[i][j]) for this lane's column j — 48 VGPRs,
    // pinned non-rematerializable by the opaque asm.
    float etr[KK];
    #pragma unroll
    for (int i = 0; i < KK; ++i) {
        etr[i] = active ? __expf(trans[i * KK + j]) : 0.0f;
        asm volatile("" : "+v"(etr[i]));
    }

    const float* emb = em + (size_t)b * TT * KK;

    // init: pcur = exp(S_0 - c), c = S_0[0]
    float s0 = start[j] + emb[j];
    float c = bcast(s0, 0);
    float pcur = active ? __expf(s0 - c) : 0.0f;

    // emission prefetch pipeline (depth PF) keeps HBM/L2 latency off the chain
    float pipe[PF];
    #pragma unroll
    for (int d = 0; d < PF; ++d) pipe[d] = emb[(1 + d) * KK + j];

    int t = 1;
    // ---- main loop: full PF-blocks, no per-substep guards ----
    while (t + PF <= len) {
        float eexp[PF];
        #pragma unroll
        for (int d = 0; d < PF; ++d) eexp[d] = __expf(pipe[d]);   // off-chain
        #pragma unroll
        for (int d = 0; d < PF; ++d) {
            int tt = t + PF + d; tt = tt < TT ? tt : TT - 1;
            pipe[d] = emb[tt * KK + j];
        }
        #pragma unroll
        for (int d = 0; d < PF; ++d) {
            float scale = eexp[d];
            const bool renorm = (d == 0) || (d == 4);
            float r = 0.0f;
            if (renorm) {
                r = bcast(pcur, 0);                 // first readlane
                scale *= __builtin_amdgcn_rcpf(r);  // overlaps RL sequence
            }
            float q0 = bcast(pcur, 0) * etr[0];
            float q1 = 0.f, q2 = 0.f, q3 = 0.f;
            #pragma unroll
            for (int k = 1; k < KK; k += 4) {
                q1 = fmaf(bcast(pcur, k),     etr[k],     q1);
                q2 = fmaf(bcast(pcur, k + 1), etr[k + 1], q2);
                q3 = fmaf(bcast(pcur, k + 2), etr[k + 2], q3);
                if (k + 3 < KK)
                    q0 = fmaf(bcast(pcur, k + 3), etr[k + 3], q0);
            }
            if (renorm) c += __logf(r);             // side chain
            float qs = (q0 + q1) + (q2 + q3);
            pcur = qs * scale;
        }
        t += PF;
    }
    // ---- tail: guarded, renorm every step (<= 7 steps) ----
    while (t < len) {
        float e = __expf(pipe[0]);
        #pragma unroll
        for (int d = 0; d < PF - 1; ++d) pipe[d] = pipe[d + 1];
        {
            float r = bcast(pcur, 0);
            float scale = e * __builtin_amdgcn_rcpf(r);
            float q0 = r * etr[0];
            float q1 = 0.f, q2 = 0.f, q3 = 0.f;
            #pragma unroll
            for (int k = 1; k < KK; k += 4) {
                q1 = fmaf(bcast(pcur, k),     etr[k],     q1);
                q2 = fmaf(bcast(pcur, k + 1), etr[k + 1], q2);
                q3 = fmaf(bcast(pcur, k + 2), etr[k + 2], q3);
                if (k + 3 < KK)
                    q0 = fmaf(bcast(pcur, k + 3), etr[k + 3], q0);
            }
            c += __logf(r);
            float qs = (q0 + q1) + (q2 + q3);
            pcur = qs * scale;
        }
        ++t;
    }

    // log_z = c + log(sum_j pcur_j * exp(end_j))
    float v = active ? pcur * __expf(endt[j]) : 0.0f;
    #pragma unroll
    for (int off = 32; off >= 1; off >>= 1) v += __shfl_xor(v, off);

    // ---- fused gold-path score (mask is prefix: m[t] == (t < len)) ----
    const int* tgb = tags + b * TT;
    float sq = 0.f;
    for (int tt2 = lane; tt2 < TT; tt2 += 64) {
        if (tt2 >= 1 && tt2 < len) {
            int tp = tgb[tt2 - 1], tc = tgb[tt2];
            sq += trans[tp * KK + tc] + emb[tt2 * KK + tc];
        }
    }
    #pragma unroll
    for (int off = 32; off >= 1; off >>= 1) sq += __shfl_xor(sq, off);

    if (lane == 0) {
        int t0 = tgb[0];
        ws[b]      = c + __logf(v);
        ws[BB + b] = sq + start[t0] + emb[t0] + endt[tgb[len - 1]];
    }
}

// ---------------- final mean reduction ----------------
__global__ __launch_bounds__(256) void crf_final(const float* __restrict__ ws,
                                                 float* __restrict__ out)
{
    __shared__ float red[256];
    float s = 0.f;
    for (int b = threadIdx.x; b < BB; b += 256) s += ws[b] - ws[BB + b];
    red[threadIdx.x] = s;
    __syncthreads();
    for (int off = 128; off > 0; off >>= 1) {
        if (threadIdx.x < off) red[threadIdx.x] += red[threadIdx.x + off];
        __syncthreads();
    }
    if (threadIdx.x == 0) out[0] = red[0] / (float)BB;
}

extern "C" void kernel_launch(void* const* d_in, const int* in_sizes, int n_in,
                              void* d_out, int out_size, void* d_ws, size_t ws_size,
                              hipStream_t stream) {
    const float* em    = (const float*)d_in[0];
    const int*   tags  = (const int*)d_in[1];
    const void*  mask  = d_in[2];
    const float* trans = (const float*)d_in[3];
    const float* start = (const float*)d_in[4];
    const float* endt  = (const float*)d_in[5];
    float* ws  = (float*)d_ws;
    float* out = (float*)d_out;

    crf_fwd  <<<BB, 64,  0, stream>>>(em, tags, mask, trans, start, endt, ws);
    crf_final<<<1,  256, 0, stream>>>(ws, out);
}

// Round 5
// 333.235 us; speedup vs baseline: 1.5203x; 1.0158x over previous
//
#include <hip/hip_runtime.h>
#include <stdint.h>

#define BB 512
#define TT 1024
#define KK 48
#define PF 8

// mask may arrive as 1-byte bools (raw numpy) or as 4-byte words.
// mask[0][0..3] are guaranteed true (len >= T/2), so the first 32-bit word is
// 0x01010101 iff byte storage.
__device__ __forceinline__ int mask_at(const void* m, int idx, bool bytes) {
    return bytes ? (int)(((const uint8_t*)m)[idx] != 0)
                 : (int)(((const int*)m)[idx] != 0);
}

// wave-uniform broadcast from a fixed lane via v_readlane_b32 (SGPR result,
// no LDS pipe, no barrier)
__device__ __forceinline__ float bcast(float v, int lane) {
    return __int_as_float(__builtin_amdgcn_readlane(__float_as_int(v), lane));
}

// ------------- forward algorithm + fused gold-path score -------------------
// One wave per batch row; lane j owns state j. Exp-domain recurrence
// p <- (E^T p) * exp(em_t), E = exp(trans) in VGPRs.
// R4 post-mortem: interleaved RL;FMA pairs pay the VALU-writes-SGPR ->
// VALU-reads-SGPR hazard (~4-6 wait states) 48x/step (~528 cyc/step
// measured). Fix: batch ALL readlanes, sched_barrier(0), then all FMAs —
// every FMA reads an SGPR written >= 48 instructions earlier (no hazard).
// Renorm every 4th step: growth/step <= 48*e^{0.1+5.5} ~= 2^14 — f32-safe.
__global__ __launch_bounds__(64, 1) void crf_fwd(
    const float* __restrict__ em, const int* __restrict__ tags,
    const void* __restrict__ mask, const float* __restrict__ trans,
    const float* __restrict__ start, const float* __restrict__ endt,
    float* __restrict__ ws)
{
    const int b = blockIdx.x;
    const int lane = threadIdx.x;
    const bool active = lane < KK;
    const int j = active ? lane : KK - 1;   // clamp for safe loads

    const bool mb = (*(const int*)mask) == 0x01010101;

    // sequence length = popcount of prefix mask
    int cnt = 0;
    for (int t = lane; t < TT; t += 64) cnt += mask_at(mask, b * TT + t, mb);
    #pragma unroll
    for (int off = 32; off >= 1; off >>= 1) cnt += __shfl_xor(cnt, off);
    const int len = cnt;

    // E[i][j] = exp(trans[i][j]) for this lane's column j
    float etr[KK];
    #pragma unroll
    for (int i = 0; i < KK; ++i) {
        etr[i] = active ? __expf(trans[i * KK + j]) : 0.0f;
        asm volatile("" : "+v"(etr[i]));
    }

    const float* emb = em + (size_t)b * TT * KK;

    // init: pcur = exp(S_0 - c), c = S_0[0]
    float s0 = start[j] + emb[j];
    float c = bcast(s0, 0);
    float pcur = active ? __expf(s0 - c) : 0.0f;

    // emission prefetch pipeline (depth PF) keeps HBM/L2 latency off the chain
    float pipe[PF];
    #pragma unroll
    for (int d = 0; d < PF; ++d) pipe[d] = emb[(1 + d) * KK + j];

    int t = 1;
    // ---- main loop: full PF-blocks, no per-substep guards ----
    while (t + PF <= len) {
        float eexp[PF];
        #pragma unroll
        for (int d = 0; d < PF; ++d) eexp[d] = __expf(pipe[d]);   // off-chain
        #pragma unroll
        for (int d = 0; d < PF; ++d) {
            int tt = t + PF + d; tt = tt < TT ? tt : TT - 1;
            pipe[d] = emb[tt * KK + j];
        }
        #pragma unroll
        for (int d = 0; d < PF; ++d) {
            // phase 1: all 48 broadcasts (no SGPR read-after-write inside)
            float s[KK];
            #pragma unroll
            for (int k = 0; k < KK; ++k) s[k] = bcast(pcur, k);
            __builtin_amdgcn_sched_barrier(0);
            // phase 2: all 48 FMAs — each s[k] written >=48 instrs ago
            float scale = eexp[d];
            const bool renorm = (d == 0) || (d == 4);
            if (renorm) scale *= __builtin_amdgcn_rcpf(s[0]);
            float q0 = s[0] * etr[0];
            float q1 = s[1] * etr[1];
            float q2 = s[2] * etr[2];
            float q3 = s[3] * etr[3];
            #pragma unroll
            for (int k = 4; k < KK; k += 4) {
                q0 = fmaf(s[k],     etr[k],     q0);
                q1 = fmaf(s[k + 1], etr[k + 1], q1);
                q2 = fmaf(s[k + 2], etr[k + 2], q2);
                q3 = fmaf(s[k + 3], etr[k + 3], q3);
            }
            if (renorm) c += __logf(s[0]);          // side chain
            float qs = (q0 + q1) + (q2 + q3);
            pcur = qs * scale;
        }
        t += PF;
    }
    // ---- tail: guarded, renorm every step (<= 7 steps) ----
    while (t < len) {
        float e = __expf(pipe[0]);
        #pragma unroll
        for (int d = 0; d < PF - 1; ++d) pipe[d] = pipe[d + 1];
        {
            float s[KK];
            #pragma unroll
            for (int k = 0; k < KK; ++k) s[k] = bcast(pcur, k);
            __builtin_amdgcn_sched_barrier(0);
            float scale = e * __builtin_amdgcn_rcpf(s[0]);
            float q0 = s[0] * etr[0];
            float q1 = s[1] * etr[1];
            float q2 = s[2] * etr[2];
            float q3 = s[3] * etr[3];
            #pragma unroll
            for (int k = 4; k < KK; k += 4) {
                q0 = fmaf(s[k],     etr[k],     q0);
                q1 = fmaf(s[k + 1], etr[k + 1], q1);
                q2 = fmaf(s[k + 2], etr[k + 2], q2);
                q3 = fmaf(s[k + 3], etr[k + 3], q3);
            }
            c += __logf(s[0]);
            float qs = (q0 + q1) + (q2 + q3);
            pcur = qs * scale;
        }
        ++t;
    }

    // log_z = c + log(sum_j pcur_j * exp(end_j))
    float v = active ? pcur * __expf(endt[j]) : 0.0f;
    #pragma unroll
    for (int off = 32; off >= 1; off >>= 1) v += __shfl_xor(v, off);

    // ---- fused gold-path score (mask is prefix: m[t] == (t < len)) ----
    const int* tgb = tags + b * TT;
    float sq = 0.f;
    for (int tt2 = lane; tt2 < TT; tt2 += 64) {
        if (tt2 >= 1 && tt2 < len) {
            int tp = tgb[tt2 - 1], tc = tgb[tt2];
            sq += trans[tp * KK + tc] + emb[tt2 * KK + tc];
        }
    }
    #pragma unroll
    for (int off = 32; off >= 1; off >>= 1) sq += __shfl_xor(sq, off);

    if (lane == 0) {
        int t0 = tgb[0];
        ws[b]      = c + __logf(v);
        ws[BB + b] = sq + start[t0] + emb[t0] + endt[tgb[len - 1]];
    }
}

// ---------------- final mean reduction ----------------
__global__ __launch_bounds__(256) void crf_final(const float* __restrict__ ws,
                                                 float* __restrict__ out)
{
    __shared__ float red[256];
    float s = 0.f;
    for (int b = threadIdx.x; b < BB; b += 256) s += ws[b] - ws[BB + b];
    red[threadIdx.x] = s;
    __syncthreads();
    for (int off = 128; off > 0; off >>= 1) {
        if (threadIdx.x < off) red[threadIdx.x] += red[threadIdx.x + off];
        __syncthreads();
    }
    if (threadIdx.x == 0) out[0] = red[0] / (float)BB;
}

extern "C" void kernel_launch(void* const* d_in, const int* in_sizes, int n_in,
                              void* d_out, int out_size, void* d_ws, size_t ws_size,
                              hipStream_t stream) {
    const float* em    = (const float*)d_in[0];
    const int*   tags  = (const int*)d_in[1];
    const void*  mask  = d_in[2];
    const float* trans = (const float*)d_in[3];
    const float* start = (const float*)d_in[4];
    const float* endt  = (const float*)d_in[5];
    float* ws  = (float*)d_ws;
    float* out = (float*)d_out;

    crf_fwd  <<<BB, 64,  0, stream>>>(em, tags, mask, trans, start, endt, ws);
    crf_final<<<1,  256, 0, stream>>>(ws, out);
}